// Round 17
// baseline (407.067 us; speedup 1.0000x reference)
//
#include <hip/hip_runtime.h>

#define NN 100000
#define NE 1200000
#define NF 64
#define NH 256
#define NC 40
#define ORDER_C 8
#define BINB 1024   // edges per level-1 binning block
#define BCAP 165000 // level-1 bucket capacity
#define NSB 782     // sub-bins of 128 rows (ceil(100000/128))
#define SBROWS 128
#define SBCAP 1920  // sub-bin capacity (expected 1535, sigma ~39)
#define NLB 100     // local sub-bins per level-1 bucket (12500/128 + 2)
#define CCAP (NE + 7 * NN)  // padded CSR capacity

typedef __attribute__((ext_vector_type(8))) short short8;
typedef __attribute__((ext_vector_type(4))) float f32x4;

// ---- bf16 helpers (RTNE pack, cheap unpack) ----
__device__ __forceinline__ unsigned bf16r(float x) {
    unsigned u = __float_as_uint(x);
    return (u + 0x7FFFu + ((u >> 16) & 1u)) >> 16;
}
__device__ __forceinline__ unsigned packbf(float lo, float hi) {
    return bf16r(lo) | (bf16r(hi) << 16);
}
__device__ __forceinline__ float bflo(unsigned u) { return __uint_as_float(u << 16); }
__device__ __forceinline__ float bfhi(unsigned u) { return __uint_as_float(u & 0xFFFF0000u); }

// ---------------- level-1 binning: 8 row-range buckets (reads edges once) ----------------

static __global__ __launch_bounds__(256) void k_bin(const int* __restrict__ rows,
                                                    const int* __restrict__ cols,
                                                    int* __restrict__ bcnt,
                                                    int* __restrict__ browb,
                                                    int* __restrict__ bcolb, int E)
{
    __shared__ int rbuf[BINB];
    __shared__ unsigned short lofs[BINB];
    __shared__ int hist[8], basew[8];
    int t = threadIdx.x;
    int e0 = blockIdx.x * BINB;
    int m = E - e0; if (m > BINB) m = BINB;
    if (t < 8) hist[t] = 0;
    __syncthreads();
    for (int i = t; i < m; i += 256) {
        int r = rows[e0 + i];
        rbuf[i] = r;
        int b = r / 12500;
        lofs[i] = (unsigned short)atomicAdd(&hist[b], 1);
    }
    __syncthreads();
    if (t < 8) basew[t] = atomicAdd(&bcnt[t], hist[t]);
    __syncthreads();
    for (int i = t; i < m; i += 256) {
        int r = rbuf[i];
        int b = r / 12500;
        size_t pos = (size_t)b * BCAP + basew[b] + lofs[i];
        browb[pos] = r;
        bcolb[pos] = cols[e0 + i];
    }
}

// ---------------- level-2 binning: bucket -> sub-bins of 128 rows (local hist) ----------------

static __global__ __launch_bounds__(256) void k_bin98(const int* __restrict__ browb,
                                                      const int* __restrict__ bcolb,
                                                      const int* __restrict__ bcnt,
                                                      int* __restrict__ sbcnt,
                                                      int* __restrict__ sbrow,
                                                      int* __restrict__ sbcol)
{
    __shared__ int rbuf[2048];
    __shared__ unsigned short lofs[2048];
    __shared__ int hist[NLB], basew[NLB];
    int t = threadIdx.x;
    int b = blockIdx.x & 7;
    int m = bcnt[b];
    int lo_sb = (b * 12500) >> 7;   // first sub-bin this bucket can touch
    const int* srcr = browb + (size_t)b * BCAP;
    const int* srcc = bcolb + (size_t)b * BCAP;
    int stride = (gridDim.x >> 3) * 2048;
    for (int base = (blockIdx.x >> 3) * 2048; base < m; base += stride) {
        int cm = m - base; if (cm > 2048) cm = 2048;
        if (t < NLB) hist[t] = 0;
        __syncthreads();
        for (int i = t; i < cm; i += 256) {
            int r = srcr[base + i];
            rbuf[i] = r;
            lofs[i] = (unsigned short)atomicAdd(&hist[(r >> 7) - lo_sb], 1);
        }
        __syncthreads();
        if (t < NLB) {
            int h = hist[t];
            basew[t] = h ? atomicAdd(&sbcnt[lo_sb + t], h) : 0;
        }
        __syncthreads();
        for (int i = t; i < cm; i += 256) {
            int r = rbuf[i];
            int sb = r >> 7;
            int pos = sb * SBCAP + basew[sb - lo_sb] + lofs[i];
            sbrow[pos] = r;
            sbcol[pos] = srcc[base + i];
        }
        __syncthreads();
    }
}

// ---------------- per-sub-bin histogram + padded total ----------------

static __global__ __launch_bounds__(256) void k_hist(const int* __restrict__ sbrow,
                                                     const int* __restrict__ sbcnt,
                                                     int* __restrict__ ghist,
                                                     int* __restrict__ sbtot)
{
    __shared__ int h[SBROWS];
    __shared__ int red[256];
    int sb = blockIdx.x;
    int t = threadIdx.x;
    int m = sbcnt[sb];
    const int* src = sbrow + (size_t)sb * SBCAP;
    if (t < SBROWS) h[t] = 0;
    __syncthreads();
    for (int i = t; i < m; i += 256) atomicAdd(&h[src[i] & 127], 1);
    __syncthreads();
    int pad = 0;
    if (t < SBROWS) {
        ghist[sb * SBROWS + t] = h[t];
        pad = (h[t] + 7) & ~7;
    }
    red[t] = pad;
    __syncthreads();
    for (int off = 128; off > 0; off >>= 1) {
        if (t < off) red[t] += red[t + off];
        __syncthreads();
    }
    if (t == 0) sbtot[sb] = red[0];
}

// ---------------- scan over sub-bin padded totals -> CSR bases ----------------

static __global__ __launch_bounds__(1024) void k_scansb(const int* __restrict__ sbtot,
                                                        int* __restrict__ sbbase,
                                                        int* __restrict__ rp, int n)
{
    __shared__ int red[1024];
    int t = threadIdx.x;
    int v = (t < NSB) ? sbtot[t] : 0;
    red[t] = v;
    __syncthreads();
    for (int off = 1; off < 1024; off <<= 1) {
        int x = (t >= off) ? red[t - off] : 0;
        __syncthreads();
        red[t] += x;
        __syncthreads();
    }
    if (t < NSB) sbbase[t] = (t == 0) ? 0 : red[t - 1];
    if (t == NSB - 1) rp[n] = red[t];
}

// ---------------- per-sub-bin CSR build: block-private contiguous slice ----------------

static __global__ __launch_bounds__(256) void k_csr(const int* __restrict__ sbrow,
                                                    const int* __restrict__ sbcol,
                                                    const int* __restrict__ sbcnt,
                                                    const int* __restrict__ ghist,
                                                    const int* __restrict__ sbbase,
                                                    int* __restrict__ rp,
                                                    float2* __restrict__ drd,
                                                    int* __restrict__ ccol, int n)
{
    __shared__ int rb[SBCAP];
    __shared__ int cb[SBCAP];
    __shared__ int sc[SBROWS], ro[SBROWS], fl[SBROWS];
    int sb = blockIdx.x;
    int t = threadIdx.x;
    int m = sbcnt[sb];
    const int* srcr = sbrow + (size_t)sb * SBCAP;
    const int* srcc = sbcol + (size_t)sb * SBCAP;
    for (int i = t; i < m; i += 256) { rb[i] = srcr[i] & 127; cb[i] = srcc[i]; }
    int h = (t < SBROWS) ? ghist[sb * SBROWS + t] : 0;
    if (t < SBROWS) { sc[t] = (h + 7) & ~7; fl[t] = 0; }
    __syncthreads();
    for (int off = 1; off < SBROWS; off <<= 1) {
        int x = (t >= off && t < SBROWS) ? sc[t - off] : 0;
        __syncthreads();
        if (t < SBROWS) sc[t] += x;
        __syncthreads();
    }
    int base = sbbase[sb];
    if (t < SBROWS) {
        ro[t] = (t == 0) ? 0 : sc[t - 1];
        int row = sb * SBROWS + t;
        if (row < n) {
            rp[row] = base + ro[t];
            float d1 = rsqrtf((float)(h + 1));
            drd[row] = make_float2(d1, (float)(h + 1) * d1);  // (dinv, sqrt(deg))
            int p = (h + 7) & ~7;
            for (int q = h; q < p; ++q) ccol[base + ro[t] + q] = n;  // pads -> zero row
        }
    }
    __syncthreads();
    for (int i = t; i < m; i += 256) {
        int r = rb[i];
        int rank = atomicAdd(&fl[r], 1);   // LDS atomic
        ccol[base + ro[r] + rank] = cb[i];
    }
}

// ---------------- pack W1/W2 into MFMA B-fragment order (bf16) ----------------

static __global__ __launch_bounds__(256) void k_pack(const float* __restrict__ W1,
                                                     const float* __restrict__ W2,
                                                     unsigned short* __restrict__ w1f,
                                                     unsigned short* __restrict__ w2f)
{
    int t = blockIdx.x * 256 + threadIdx.x;
    if (t < 2048) {
        int lane = t & 63;
        int g = lane >> 4, col = (lane & 15) + ((t >> 6) & 15) * 16;
        int s = t >> 10;
        unsigned short* p = w1f + (size_t)t * 8;
        #pragma unroll
        for (int e = 0; e < 8; ++e) {
            int k = 32 * s + 8 * g + e;
            p[e] = (unsigned short)bf16r(W1[k * NH + col]);
        }
    } else if (t < 2048 + 1536) {
        int u = t - 2048;
        int lane = u & 63;
        int tile = u >> 6;
        int nt = tile % 3, s = tile / 3;
        int g = lane >> 4, col = (lane & 15) + nt * 16;
        unsigned short* p = w2f + (size_t)u * 8;
        #pragma unroll
        for (int e = 0; e < 8; ++e) {
            int k = 32 * s + 8 * g + e;
            p[e] = (col < NC) ? (unsigned short)bf16r(W2[k * NC + col]) : 0;
        }
    }
}

// ---------------- init: y = 0.5*x (f32) ; g halves = bf16(dinv*0.5*x) ; zero rows ----------------
// g layout per buffer: [half][n+1 rows][8 uint2]  (half-row = 64B = one L2 line)

static __global__ __launch_bounds__(256) void k_init(const float4* __restrict__ x4,
                                                     float4* __restrict__ y4,
                                                     uint2* __restrict__ ga,
                                                     uint2* __restrict__ gbp,
                                                     const float2* __restrict__ drd,
                                                     int nchunk)
{
    int i = blockIdx.x * 256 + threadIdx.x;
    if (i >= nchunk) {
        int extra = i - nchunk;
        if (extra < 32) {   // zero row NN in both halves of both buffers
            uint2* buf = (extra & 16) ? gbp : ga;
            int k = extra & 15;
            int half = k >> 3, slot = k & 7;
            buf[(size_t)half * (NN + 1) * 8 + (size_t)NN * 8 + slot] = make_uint2(0u, 0u);
        }
        return;
    }
    float d1 = drd[i >> 3].x;
    float4 a = x4[i * 2], b = x4[i * 2 + 1];
    a.x *= 0.5f; a.y *= 0.5f; a.z *= 0.5f; a.w *= 0.5f;
    b.x *= 0.5f; b.y *= 0.5f; b.z *= 0.5f; b.w *= 0.5f;
    y4[i * 2] = a; y4[i * 2 + 1] = b;
    int row = i >> 3, q = i & 7;
    int half = q >> 2, slot2 = (q & 3) * 2;
    uint4* dst = (uint4*)&ga[(size_t)half * (NN + 1) * 8 + (size_t)row * 8 + slot2];
    *dst = make_uint4(packbf(a.x * d1, a.y * d1), packbf(a.z * d1, a.w * d1),
                      packbf(b.x * d1, b.y * d1), packbf(b.z * d1, b.w * d1));
}

// ---------------- SpMM on one feature half: 8 rows/wave, 8 lanes x uint2 (64B rows) ----------
// S = sum_e g[col_e] + g[row]; h_next = dinv*S; g_next = dinv*h_next.
// ACC iterations fold y += h_k (= g_k[row]*rd) + h_{k+1}. yh pre-offset by half*8.

template<bool ACC, bool WRITEG>
static __global__ __launch_bounds__(256) void k_spmm_h(const uint2* __restrict__ gb,
                                                       uint2* __restrict__ go,
                                                       float4* __restrict__ yh,
                                                       const int* __restrict__ rp,
                                                       const int* __restrict__ ccol,
                                                       const float2* __restrict__ drd, int n)
{
    int wid  = (blockIdx.x * 256 + threadIdx.x) >> 6;
    int lane = threadIdx.x & 63;
    int row  = wid * 8 + (lane >> 3);
    int j    = lane & 7;             // uint2 slot (4 bf16 feats) within 64B half-row
    if (row >= n) return;
    int s = rp[row], e = rp[row + 1];   // e-s is a multiple of 8

    float a0 = 0.f, a1 = 0.f, a2 = 0.f, a3 = 0.f;   // chain A
    float b0 = 0.f, b1 = 0.f, b2 = 0.f, b3 = 0.f;   // chain B
    for (int i = s; i < e; i += 8) {
        int4 cA = *(const int4*)&ccol[i];
        int4 cB = *(const int4*)&ccol[i + 4];
        uint2 h0 = gb[(size_t)cA.x * 8 + j];
        uint2 h1 = gb[(size_t)cA.y * 8 + j];
        uint2 h2 = gb[(size_t)cA.z * 8 + j];
        uint2 h3 = gb[(size_t)cA.w * 8 + j];
        uint2 h4 = gb[(size_t)cB.x * 8 + j];
        uint2 h5 = gb[(size_t)cB.y * 8 + j];
        uint2 h6 = gb[(size_t)cB.z * 8 + j];
        uint2 h7 = gb[(size_t)cB.w * 8 + j];
        a0 += bflo(h0.x); a1 += bfhi(h0.x); a2 += bflo(h0.y); a3 += bfhi(h0.y);
        b0 += bflo(h1.x); b1 += bfhi(h1.x); b2 += bflo(h1.y); b3 += bfhi(h1.y);
        a0 += bflo(h2.x); a1 += bfhi(h2.x); a2 += bflo(h2.y); a3 += bfhi(h2.y);
        b0 += bflo(h3.x); b1 += bfhi(h3.x); b2 += bflo(h3.y); b3 += bfhi(h3.y);
        a0 += bflo(h4.x); a1 += bfhi(h4.x); a2 += bflo(h4.y); a3 += bfhi(h4.y);
        b0 += bflo(h5.x); b1 += bfhi(h5.x); b2 += bflo(h5.y); b3 += bfhi(h5.y);
        a0 += bflo(h6.x); a1 += bfhi(h6.x); a2 += bflo(h6.y); a3 += bfhi(h6.y);
        b0 += bflo(h7.x); b1 += bfhi(h7.x); b2 += bflo(h7.y); b3 += bfhi(h7.y);
    }

    float2 dr = drd[row];
    uint2 gs = gb[(size_t)row * 8 + j];
    float g0 = bflo(gs.x), g1 = bfhi(gs.x), g2 = bflo(gs.y), g3 = bfhi(gs.y);
    float s0 = (a0 + b0) + g0;
    float s1 = (a1 + b1) + g1;
    float s2 = (a2 + b2) + g2;
    float s3 = (a3 + b3) + g3;
    float h0 = dr.x * s0, h1 = dr.x * s1, h2 = dr.x * s2, h3 = dr.x * s3;  // h_{k+1}
    if (WRITEG)
        go[(size_t)row * 8 + j] = make_uint2(packbf(dr.x * h0, dr.x * h1),
                                             packbf(dr.x * h2, dr.x * h3));  // g_{k+1}
    if (ACC) {
        float4 yv = yh[(size_t)row * 16 + j];
        yv.x += fmaf(g0, dr.y, h0);               // h_k + h_{k+1}
        yv.y += fmaf(g1, dr.y, h1);
        yv.z += fmaf(g2, dr.y, h2);
        yv.w += fmaf(g3, dr.y, h3);
        yh[(size_t)row * 16 + j] = yv;
    }
}

// ---------------- MFMA MLP: 64 rows/block, 4 waves (unchanged) ----------------

#define YSTR 72    // shorts per ys row
#define HSTR 264   // shorts per hs row

static __global__ __launch_bounds__(256) void k_mlp(const float4* __restrict__ y4,
                                                    const short8* __restrict__ w1f,
                                                    const short8* __restrict__ w2f,
                                                    const float* __restrict__ b1,
                                                    const float* __restrict__ b2,
                                                    float* __restrict__ out, int n)
{
    __shared__ short lds[64 * HSTR];   // 33.8 KB; first 64*YSTR shorts = ys
    int t = threadIdx.x;
    int lane = t & 63;
    int w = t >> 6;
    int base = blockIdx.x * 64;
    const float S = 1.f / 9.f;

    {
        int r = t >> 2, q = t & 3;
        int row = base + r;
        unsigned v[8];
        if (row < n) {
            const float4* yp = y4 + (size_t)row * 16 + q * 4;
            #pragma unroll
            for (int i = 0; i < 4; ++i) {
                float4 f = yp[i];
                v[i * 2]     = packbf(f.x * S, f.y * S);
                v[i * 2 + 1] = packbf(f.z * S, f.w * S);
            }
        } else {
            #pragma unroll
            for (int i = 0; i < 8; ++i) v[i] = 0;
        }
        uint4* dst = (uint4*)&lds[r * YSTR + q * 16];
        dst[0] = make_uint4(v[0], v[1], v[2], v[3]);
        dst[1] = make_uint4(v[4], v[5], v[6], v[7]);
    }
    __syncthreads();

    int m = lane & 15, g = lane >> 4;

    f32x4 acc[4][4];
    {
        short8 a[4][2];
        #pragma unroll
        for (int mt = 0; mt < 4; ++mt)
            #pragma unroll
            for (int s = 0; s < 2; ++s)
                a[mt][s] = *(const short8*)&lds[(mt * 16 + m) * YSTR + s * 32 + g * 8];
        #pragma unroll
        for (int nt4 = 0; nt4 < 4; ++nt4) {
            int nt = w * 4 + nt4;
            short8 b0  = w1f[nt * 64 + lane];
            short8 b1v = w1f[(16 + nt) * 64 + lane];
            float bias = b1[nt * 16 + m];
            #pragma unroll
            for (int mt = 0; mt < 4; ++mt) {
                f32x4 c = {bias, bias, bias, bias};
                c = __builtin_amdgcn_mfma_f32_16x16x32_bf16(a[mt][0], b0,  c, 0, 0, 0);
                c = __builtin_amdgcn_mfma_f32_16x16x32_bf16(a[mt][1], b1v, c, 0, 0, 0);
                acc[mt][nt4] = c;
            }
        }
    }
    __syncthreads();

    {
        #pragma unroll
        for (int mt = 0; mt < 4; ++mt)
            #pragma unroll
            for (int nt4 = 0; nt4 < 4; ++nt4) {
                int col = w * 64 + nt4 * 16 + m;
                #pragma unroll
                for (int r = 0; r < 4; ++r) {
                    float hv = fmaxf(acc[mt][nt4][r], 0.f);
                    lds[(mt * 16 + g * 4 + r) * HSTR + col] = (short)bf16r(hv);
                }
            }
    }
    __syncthreads();

    {
        short8 a2[8];
        #pragma unroll
        for (int s = 0; s < 8; ++s)
            a2[s] = *(const short8*)&lds[(w * 16 + m) * HSTR + s * 32 + g * 8];
        #pragma unroll
        for (int nt = 0; nt < 3; ++nt) {
            int col = nt * 16 + m;
            float bias = (col < NC) ? b2[col] : 0.f;
            f32x4 c = {bias, bias, bias, bias};
            #pragma unroll
            for (int s = 0; s < 8; ++s)
                c = __builtin_amdgcn_mfma_f32_16x16x32_bf16(a2[s], w2f[(s * 3 + nt) * 64 + lane], c, 0, 0, 0);
            if (col < NC) {
                #pragma unroll
                for (int r = 0; r < 4; ++r) {
                    int row = base + w * 16 + g * 4 + r;
                    if (row < n) out[(size_t)row * NC + col] = c[r];
                }
            }
        }
    }
}

// ---------------- launch ----------------

extern "C" void kernel_launch(void* const* d_in, const int* in_sizes, int n_in,
                              void* d_out, int out_size, void* d_ws, size_t ws_size,
                              hipStream_t stream)
{
    const float* x  = (const float*)d_in[0];
    const int*   ei = (const int*)d_in[1];
    const float* W1 = (const float*)d_in[2];
    const float* b1 = (const float*)d_in[3];
    const float* W2 = (const float*)d_in[4];
    const float* b2 = (const float*)d_in[5];
    float* out = (float*)d_out;

    const int n = NN, E = NE;

    char* ws = (char*)d_ws;
    size_t off = 0;
    auto alloc = [&](size_t bytes) -> void* {
        void* p = ws + off;
        off = (off + bytes + 255) & ~(size_t)255;
        return p;
    };
    int*    rp     = (int*)   alloc((size_t)(n + 1) * 4);
    float2* drd    = (float2*)alloc((size_t)n * 8);
    int*    bcnt   = (int*)   alloc(8 * 4);
    int*    sbcnt  = (int*)   alloc(NSB * 4);
    int*    sbtot  = (int*)   alloc(NSB * 4);
    int*    sbbase = (int*)   alloc(NSB * 4);
    int*    browb  = (int*)   alloc((size_t)8 * BCAP * 4);
    int*    bcolb  = (int*)   alloc((size_t)8 * BCAP * 4);
    int*    sbrow  = (int*)   alloc((size_t)NSB * SBCAP * 4);
    int*    sbcol  = (int*)   alloc((size_t)NSB * SBCAP * 4);
    int*    ghist  = (int*)   alloc((size_t)NSB * SBROWS * 4);
    int*    ccol   = (int*)   alloc((size_t)CCAP * 4);
    unsigned short* w1f = (unsigned short*)alloc(2048 * 8 * 2);
    unsigned short* w2f = (unsigned short*)alloc(1536 * 8 * 2);
    uint2* gA   = (uint2*)alloc((size_t)2 * (n + 1) * 8 * 8);  // [2 halves][n+1][8 uint2]
    uint2* gB   = (uint2*)alloc((size_t)2 * (n + 1) * 8 * 8);
    float* y    = (float*)alloc((size_t)n * NF * 4);           // f32 accumulator

    hipMemsetAsync(bcnt, 0, 8 * 4, stream);
    hipMemsetAsync(sbcnt, 0, NSB * 4, stream);

    const int* rows = ei;
    const int* cols = ei + E;

    k_bin   <<<(E + BINB - 1) / BINB, 256, 0, stream>>>(rows, cols, bcnt, browb, bcolb, E);
    k_bin98 <<<640, 256, 0, stream>>>(browb, bcolb, bcnt, sbcnt, sbrow, sbcol);
    k_hist  <<<NSB, 256, 0, stream>>>(sbrow, sbcnt, ghist, sbtot);
    k_scansb<<<1, 1024, 0, stream>>>(sbtot, sbbase, rp, n);
    k_csr   <<<NSB, 256, 0, stream>>>(sbrow, sbcol, sbcnt, ghist, sbbase, rp, drd, ccol, n);
    k_pack  <<<14, 256, 0, stream>>>(W1, W2, w1f, w2f);

    int nchunk = n * 8;
    k_init<<<(nchunk + 32 + 255) / 256, 256, 0, stream>>>((const float4*)x, (float4*)y,
                                                          gA, gB, drd, nchunk);

    const size_t HSTRIDE = (size_t)(NN + 1) * 8;   // uint2 per half
    int spmm_blocks = (n + 31) / 32;               // 8 rows/wave, 4 waves/block
    for (int half = 0; half < 2; ++half) {
        uint2* cur = gA + (size_t)half * HSTRIDE;
        uint2* nxt = gB + (size_t)half * HSTRIDE;
        float4* yh = (float4*)y + half * 8;
        for (int it = 0; it < ORDER_C; ++it) {
            bool acc = (it & 1) != 0;
            bool wg  = (it != ORDER_C - 1);
            if (acc && wg)
                k_spmm_h<true, true><<<spmm_blocks, 256, 0, stream>>>(cur, nxt, yh,
                                                                      rp, ccol, drd, n);
            else if (acc)
                k_spmm_h<true, false><<<spmm_blocks, 256, 0, stream>>>(cur, nxt, yh,
                                                                       rp, ccol, drd, n);
            else
                k_spmm_h<false, true><<<spmm_blocks, 256, 0, stream>>>(cur, nxt, yh,
                                                                       rp, ccol, drd, n);
            uint2* tswap = cur; cur = nxt; nxt = tswap;
        }
    }

    k_mlp<<<(n + 63) / 64, 256, 0, stream>>>((const float4*)y, (const short8*)w1f,
                                             (const short8*)w2f, b1, b2, out, n);
}

// Round 18
// 326.982 us; speedup vs baseline: 1.2449x; 1.2449x over previous
//
#include <hip/hip_runtime.h>

#define NN 100000
#define NE 1200000
#define NF 64
#define NH 256
#define NC 40
#define ORDER_C 8
#define BINB 1024   // edges per level-1 binning block
#define BCAP 165000 // level-1 bucket capacity
#define NSB 782     // sub-bins of 128 rows (ceil(100000/128))
#define SBROWS 128
#define SBCAP 1920  // sub-bin capacity (expected 1535, sigma ~39)
#define NLB 100     // local sub-bins per level-1 bucket (12500/128 + 2)
#define CCAP (NE + 7 * NN)  // padded CSR capacity

typedef __attribute__((ext_vector_type(8))) short short8;
typedef __attribute__((ext_vector_type(4))) float f32x4;

// ---- bf16 helpers (RTNE pack, cheap unpack) ----
__device__ __forceinline__ unsigned bf16r(float x) {
    unsigned u = __float_as_uint(x);
    return (u + 0x7FFFu + ((u >> 16) & 1u)) >> 16;
}
__device__ __forceinline__ unsigned packbf(float lo, float hi) {
    return bf16r(lo) | (bf16r(hi) << 16);
}
__device__ __forceinline__ float bflo(unsigned u) { return __uint_as_float(u << 16); }
__device__ __forceinline__ float bfhi(unsigned u) { return __uint_as_float(u & 0xFFFF0000u); }

// ---------------- level-1 binning: 8 row-range buckets (reads edges once) ----------------

static __global__ __launch_bounds__(256) void k_bin(const int* __restrict__ rows,
                                                    const int* __restrict__ cols,
                                                    int* __restrict__ bcnt,
                                                    int* __restrict__ browb,
                                                    int* __restrict__ bcolb, int E)
{
    __shared__ int rbuf[BINB];
    __shared__ unsigned short lofs[BINB];
    __shared__ int hist[8], basew[8];
    int t = threadIdx.x;
    int e0 = blockIdx.x * BINB;
    int m = E - e0; if (m > BINB) m = BINB;
    if (t < 8) hist[t] = 0;
    __syncthreads();
    for (int i = t; i < m; i += 256) {
        int r = rows[e0 + i];
        rbuf[i] = r;
        int b = r / 12500;
        lofs[i] = (unsigned short)atomicAdd(&hist[b], 1);
    }
    __syncthreads();
    if (t < 8) basew[t] = atomicAdd(&bcnt[t], hist[t]);
    __syncthreads();
    for (int i = t; i < m; i += 256) {
        int r = rbuf[i];
        int b = r / 12500;
        size_t pos = (size_t)b * BCAP + basew[b] + lofs[i];
        browb[pos] = r;
        bcolb[pos] = cols[e0 + i];
    }
}

// ---------------- level-2 binning: bucket -> sub-bins of 128 rows (local hist) ----------------

static __global__ __launch_bounds__(256) void k_bin98(const int* __restrict__ browb,
                                                      const int* __restrict__ bcolb,
                                                      const int* __restrict__ bcnt,
                                                      int* __restrict__ sbcnt,
                                                      int* __restrict__ sbrow,
                                                      int* __restrict__ sbcol)
{
    __shared__ int rbuf[2048];
    __shared__ unsigned short lofs[2048];
    __shared__ int hist[NLB], basew[NLB];
    int t = threadIdx.x;
    int b = blockIdx.x & 7;
    int m = bcnt[b];
    int lo_sb = (b * 12500) >> 7;   // first sub-bin this bucket can touch
    const int* srcr = browb + (size_t)b * BCAP;
    const int* srcc = bcolb + (size_t)b * BCAP;
    int stride = (gridDim.x >> 3) * 2048;
    for (int base = (blockIdx.x >> 3) * 2048; base < m; base += stride) {
        int cm = m - base; if (cm > 2048) cm = 2048;
        if (t < NLB) hist[t] = 0;
        __syncthreads();
        for (int i = t; i < cm; i += 256) {
            int r = srcr[base + i];
            rbuf[i] = r;
            lofs[i] = (unsigned short)atomicAdd(&hist[(r >> 7) - lo_sb], 1);
        }
        __syncthreads();
        if (t < NLB) {
            int h = hist[t];
            basew[t] = h ? atomicAdd(&sbcnt[lo_sb + t], h) : 0;
        }
        __syncthreads();
        for (int i = t; i < cm; i += 256) {
            int r = rbuf[i];
            int sb = r >> 7;
            int pos = sb * SBCAP + basew[sb - lo_sb] + lofs[i];
            sbrow[pos] = r;
            sbcol[pos] = srcc[base + i];
        }
        __syncthreads();
    }
}

// ---------------- per-sub-bin histogram + padded total ----------------

static __global__ __launch_bounds__(256) void k_hist(const int* __restrict__ sbrow,
                                                     const int* __restrict__ sbcnt,
                                                     int* __restrict__ ghist,
                                                     int* __restrict__ sbtot)
{
    __shared__ int h[SBROWS];
    __shared__ int red[256];
    int sb = blockIdx.x;
    int t = threadIdx.x;
    int m = sbcnt[sb];
    const int* src = sbrow + (size_t)sb * SBCAP;
    if (t < SBROWS) h[t] = 0;
    __syncthreads();
    for (int i = t; i < m; i += 256) atomicAdd(&h[src[i] & 127], 1);
    __syncthreads();
    int pad = 0;
    if (t < SBROWS) {
        ghist[sb * SBROWS + t] = h[t];
        pad = (h[t] + 7) & ~7;
    }
    red[t] = pad;
    __syncthreads();
    for (int off = 128; off > 0; off >>= 1) {
        if (t < off) red[t] += red[t + off];
        __syncthreads();
    }
    if (t == 0) sbtot[sb] = red[0];
}

// ---------------- scan over sub-bin padded totals -> CSR bases ----------------

static __global__ __launch_bounds__(1024) void k_scansb(const int* __restrict__ sbtot,
                                                        int* __restrict__ sbbase,
                                                        int* __restrict__ rp, int n)
{
    __shared__ int red[1024];
    int t = threadIdx.x;
    int v = (t < NSB) ? sbtot[t] : 0;
    red[t] = v;
    __syncthreads();
    for (int off = 1; off < 1024; off <<= 1) {
        int x = (t >= off) ? red[t - off] : 0;
        __syncthreads();
        red[t] += x;
        __syncthreads();
    }
    if (t < NSB) sbbase[t] = (t == 0) ? 0 : red[t - 1];
    if (t == NSB - 1) rp[n] = red[t];
}

// ---------------- per-sub-bin CSR build: block-private contiguous slice ----------------
// All ccol lines of the slice are written by THIS block only -> one writeback/line.

static __global__ __launch_bounds__(256) void k_csr(const int* __restrict__ sbrow,
                                                    const int* __restrict__ sbcol,
                                                    const int* __restrict__ sbcnt,
                                                    const int* __restrict__ ghist,
                                                    const int* __restrict__ sbbase,
                                                    int* __restrict__ rp,
                                                    float2* __restrict__ drd,
                                                    int* __restrict__ ccol, int n)
{
    __shared__ int rb[SBCAP];
    __shared__ int cb[SBCAP];
    __shared__ int sc[SBROWS], ro[SBROWS], fl[SBROWS];
    int sb = blockIdx.x;
    int t = threadIdx.x;
    int m = sbcnt[sb];
    const int* srcr = sbrow + (size_t)sb * SBCAP;
    const int* srcc = sbcol + (size_t)sb * SBCAP;
    for (int i = t; i < m; i += 256) { rb[i] = srcr[i] & 127; cb[i] = srcc[i]; }
    int h = (t < SBROWS) ? ghist[sb * SBROWS + t] : 0;
    if (t < SBROWS) { sc[t] = (h + 7) & ~7; fl[t] = 0; }
    __syncthreads();
    for (int off = 1; off < SBROWS; off <<= 1) {
        int x = (t >= off && t < SBROWS) ? sc[t - off] : 0;
        __syncthreads();
        if (t < SBROWS) sc[t] += x;
        __syncthreads();
    }
    int base = sbbase[sb];
    if (t < SBROWS) {
        ro[t] = (t == 0) ? 0 : sc[t - 1];
        int row = sb * SBROWS + t;
        if (row < n) {
            rp[row] = base + ro[t];
            float d1 = rsqrtf((float)(h + 1));
            drd[row] = make_float2(d1, (float)(h + 1) * d1);  // (dinv, sqrt(deg))
            int p = (h + 7) & ~7;
            for (int q = h; q < p; ++q) ccol[base + ro[t] + q] = n;  // pads -> zero row
        }
    }
    __syncthreads();
    for (int i = t; i < m; i += 256) {
        int r = rb[i];
        int rank = atomicAdd(&fl[r], 1);   // LDS atomic
        ccol[base + ro[r] + rank] = cb[i];
    }
}

// ---------------- pack W1/W2 into MFMA B-fragment order (bf16) ----------------

static __global__ __launch_bounds__(256) void k_pack(const float* __restrict__ W1,
                                                     const float* __restrict__ W2,
                                                     unsigned short* __restrict__ w1f,
                                                     unsigned short* __restrict__ w2f)
{
    int t = blockIdx.x * 256 + threadIdx.x;
    if (t < 2048) {
        int lane = t & 63;
        int g = lane >> 4, col = (lane & 15) + ((t >> 6) & 15) * 16;
        int s = t >> 10;
        unsigned short* p = w1f + (size_t)t * 8;
        #pragma unroll
        for (int e = 0; e < 8; ++e) {
            int k = 32 * s + 8 * g + e;
            p[e] = (unsigned short)bf16r(W1[k * NH + col]);
        }
    } else if (t < 2048 + 1536) {
        int u = t - 2048;
        int lane = u & 63;
        int tile = u >> 6;
        int nt = tile % 3, s = tile / 3;
        int g = lane >> 4, col = (lane & 15) + nt * 16;
        unsigned short* p = w2f + (size_t)u * 8;
        #pragma unroll
        for (int e = 0; e < 8; ++e) {
            int k = 32 * s + 8 * g + e;
            p[e] = (col < NC) ? (unsigned short)bf16r(W2[k * NC + col]) : 0;
        }
    }
}

// ---------------- init: y = 0.5*x (f32) ; g = bf16(dinv*0.5*x) ; zero row n ----------------

static __global__ __launch_bounds__(256) void k_init(const float4* __restrict__ x4,
                                                     float4* __restrict__ y4,
                                                     uint4* __restrict__ ga,
                                                     uint4* __restrict__ gbp,
                                                     const float2* __restrict__ drd,
                                                     int nchunk)
{
    int i = blockIdx.x * 256 + threadIdx.x;
    if (i >= nchunk) {
        if (i < nchunk + 8) {   // zero row n in both ping and pong
            uint4 z = make_uint4(0, 0, 0, 0);
            ga[i] = z; gbp[i] = z;
        }
        return;
    }
    float d1 = drd[i >> 3].x;
    float4 a = x4[i * 2], b = x4[i * 2 + 1];
    a.x *= 0.5f; a.y *= 0.5f; a.z *= 0.5f; a.w *= 0.5f;
    b.x *= 0.5f; b.y *= 0.5f; b.z *= 0.5f; b.w *= 0.5f;
    y4[i * 2] = a; y4[i * 2 + 1] = b;
    ga[i] = make_uint4(packbf(a.x * d1, a.y * d1), packbf(a.z * d1, a.w * d1),
                       packbf(b.x * d1, b.y * d1), packbf(b.z * d1, b.w * d1));
}

// ---------------- SpMM on g = dinv*h: 4 rows/wave, padded-8 CSR, unroll 8 ----------------
// S = sum_e g[col_e] + g[row]; h_next = dinv*S; g_next = dinv*h_next.
// ACC iterations fold y += h_k (= g_k[row]*rd) + h_{k+1}.

template<bool ACC, bool WRITEG>
static __global__ __launch_bounds__(256) void k_spmm(const uint2* __restrict__ gb,
                                                     uint2* __restrict__ go,
                                                     float4* __restrict__ y4,
                                                     const int* __restrict__ rp,
                                                     const int* __restrict__ ccol,
                                                     const float2* __restrict__ drd, int n)
{
    int wid  = (blockIdx.x * 256 + threadIdx.x) >> 6;
    int lane = threadIdx.x & 63;
    int row  = wid * 4 + (lane >> 4);
    int j    = lane & 15;            // uint2 slot (4 bf16 feats) within 128B row
    if (row >= n) return;
    int s = rp[row], e = rp[row + 1];   // e-s is a multiple of 8

    float a0 = 0.f, a1 = 0.f, a2 = 0.f, a3 = 0.f;   // chain A
    float b0 = 0.f, b1 = 0.f, b2 = 0.f, b3 = 0.f;   // chain B
    for (int i = s; i < e; i += 8) {
        int4 cA = *(const int4*)&ccol[i];
        int4 cB = *(const int4*)&ccol[i + 4];
        uint2 h0 = gb[(size_t)cA.x * 16 + j];
        uint2 h1 = gb[(size_t)cA.y * 16 + j];
        uint2 h2 = gb[(size_t)cA.z * 16 + j];
        uint2 h3 = gb[(size_t)cA.w * 16 + j];
        uint2 h4 = gb[(size_t)cB.x * 16 + j];
        uint2 h5 = gb[(size_t)cB.y * 16 + j];
        uint2 h6 = gb[(size_t)cB.z * 16 + j];
        uint2 h7 = gb[(size_t)cB.w * 16 + j];
        a0 += bflo(h0.x); a1 += bfhi(h0.x); a2 += bflo(h0.y); a3 += bfhi(h0.y);
        b0 += bflo(h1.x); b1 += bfhi(h1.x); b2 += bflo(h1.y); b3 += bfhi(h1.y);
        a0 += bflo(h2.x); a1 += bfhi(h2.x); a2 += bflo(h2.y); a3 += bfhi(h2.y);
        b0 += bflo(h3.x); b1 += bfhi(h3.x); b2 += bflo(h3.y); b3 += bfhi(h3.y);
        a0 += bflo(h4.x); a1 += bfhi(h4.x); a2 += bflo(h4.y); a3 += bfhi(h4.y);
        b0 += bflo(h5.x); b1 += bfhi(h5.x); b2 += bflo(h5.y); b3 += bfhi(h5.y);
        a0 += bflo(h6.x); a1 += bfhi(h6.x); a2 += bflo(h6.y); a3 += bfhi(h6.y);
        b0 += bflo(h7.x); b1 += bfhi(h7.x); b2 += bflo(h7.y); b3 += bfhi(h7.y);
    }

    float2 dr = drd[row];
    uint2 gs = gb[(size_t)row * 16 + j];
    float g0 = bflo(gs.x), g1 = bfhi(gs.x), g2 = bflo(gs.y), g3 = bfhi(gs.y);
    float s0 = (a0 + b0) + g0;
    float s1 = (a1 + b1) + g1;
    float s2 = (a2 + b2) + g2;
    float s3 = (a3 + b3) + g3;
    float h0 = dr.x * s0, h1 = dr.x * s1, h2 = dr.x * s2, h3 = dr.x * s3;  // h_{k+1}
    if (WRITEG)
        go[(size_t)row * 16 + j] = make_uint2(packbf(dr.x * h0, dr.x * h1),
                                              packbf(dr.x * h2, dr.x * h3));  // g_{k+1}
    if (ACC) {
        float4 yv = y4[(size_t)row * 16 + j];
        yv.x += fmaf(g0, dr.y, h0);               // h_k + h_{k+1}
        yv.y += fmaf(g1, dr.y, h1);
        yv.z += fmaf(g2, dr.y, h2);
        yv.w += fmaf(g3, dr.y, h3);
        y4[(size_t)row * 16 + j] = yv;
    }
}

// ---------------- MFMA MLP: 64 rows/block, 4 waves (unchanged) ----------------

#define YSTR 72    // shorts per ys row
#define HSTR 264   // shorts per hs row

static __global__ __launch_bounds__(256) void k_mlp(const float4* __restrict__ y4,
                                                    const short8* __restrict__ w1f,
                                                    const short8* __restrict__ w2f,
                                                    const float* __restrict__ b1,
                                                    const float* __restrict__ b2,
                                                    float* __restrict__ out, int n)
{
    __shared__ short lds[64 * HSTR];   // 33.8 KB; first 64*YSTR shorts = ys
    int t = threadIdx.x;
    int lane = t & 63;
    int w = t >> 6;
    int base = blockIdx.x * 64;
    const float S = 1.f / 9.f;

    {
        int r = t >> 2, q = t & 3;
        int row = base + r;
        unsigned v[8];
        if (row < n) {
            const float4* yp = y4 + (size_t)row * 16 + q * 4;
            #pragma unroll
            for (int i = 0; i < 4; ++i) {
                float4 f = yp[i];
                v[i * 2]     = packbf(f.x * S, f.y * S);
                v[i * 2 + 1] = packbf(f.z * S, f.w * S);
            }
        } else {
            #pragma unroll
            for (int i = 0; i < 8; ++i) v[i] = 0;
        }
        uint4* dst = (uint4*)&lds[r * YSTR + q * 16];
        dst[0] = make_uint4(v[0], v[1], v[2], v[3]);
        dst[1] = make_uint4(v[4], v[5], v[6], v[7]);
    }
    __syncthreads();

    int m = lane & 15, g = lane >> 4;

    f32x4 acc[4][4];
    {
        short8 a[4][2];
        #pragma unroll
        for (int mt = 0; mt < 4; ++mt)
            #pragma unroll
            for (int s = 0; s < 2; ++s)
                a[mt][s] = *(const short8*)&lds[(mt * 16 + m) * YSTR + s * 32 + g * 8];
        #pragma unroll
        for (int nt4 = 0; nt4 < 4; ++nt4) {
            int nt = w * 4 + nt4;
            short8 b0  = w1f[nt * 64 + lane];
            short8 b1v = w1f[(16 + nt) * 64 + lane];
            float bias = b1[nt * 16 + m];
            #pragma unroll
            for (int mt = 0; mt < 4; ++mt) {
                f32x4 c = {bias, bias, bias, bias};
                c = __builtin_amdgcn_mfma_f32_16x16x32_bf16(a[mt][0], b0,  c, 0, 0, 0);
                c = __builtin_amdgcn_mfma_f32_16x16x32_bf16(a[mt][1], b1v, c, 0, 0, 0);
                acc[mt][nt4] = c;
            }
        }
    }
    __syncthreads();

    {
        #pragma unroll
        for (int mt = 0; mt < 4; ++mt)
            #pragma unroll
            for (int nt4 = 0; nt4 < 4; ++nt4) {
                int col = w * 64 + nt4 * 16 + m;
                #pragma unroll
                for (int r = 0; r < 4; ++r) {
                    float hv = fmaxf(acc[mt][nt4][r], 0.f);
                    lds[(mt * 16 + g * 4 + r) * HSTR + col] = (short)bf16r(hv);
                }
            }
    }
    __syncthreads();

    {
        short8 a2[8];
        #pragma unroll
        for (int s = 0; s < 8; ++s)
            a2[s] = *(const short8*)&lds[(w * 16 + m) * HSTR + s * 32 + g * 8];
        #pragma unroll
        for (int nt = 0; nt < 3; ++nt) {
            int col = nt * 16 + m;
            float bias = (col < NC) ? b2[col] : 0.f;
            f32x4 c = {bias, bias, bias, bias};
            #pragma unroll
            for (int s = 0; s < 8; ++s)
                c = __builtin_amdgcn_mfma_f32_16x16x32_bf16(a2[s], w2f[(s * 3 + nt) * 64 + lane], c, 0, 0, 0);
            if (col < NC) {
                #pragma unroll
                for (int r = 0; r < 4; ++r) {
                    int row = base + w * 16 + g * 4 + r;
                    if (row < n) out[(size_t)row * NC + col] = c[r];
                }
            }
        }
    }
}

// ---------------- launch ----------------

extern "C" void kernel_launch(void* const* d_in, const int* in_sizes, int n_in,
                              void* d_out, int out_size, void* d_ws, size_t ws_size,
                              hipStream_t stream)
{
    const float* x  = (const float*)d_in[0];
    const int*   ei = (const int*)d_in[1];
    const float* W1 = (const float*)d_in[2];
    const float* b1 = (const float*)d_in[3];
    const float* W2 = (const float*)d_in[4];
    const float* b2 = (const float*)d_in[5];
    float* out = (float*)d_out;

    const int n = NN, E = NE;

    char* ws = (char*)d_ws;
    size_t off = 0;
    auto alloc = [&](size_t bytes) -> void* {
        void* p = ws + off;
        off = (off + bytes + 255) & ~(size_t)255;
        return p;
    };
    int*    rp     = (int*)   alloc((size_t)(n + 1) * 4);
    float2* drd    = (float2*)alloc((size_t)n * 8);
    int*    bcnt   = (int*)   alloc(8 * 4);
    int*    sbcnt  = (int*)   alloc(NSB * 4);
    int*    sbtot  = (int*)   alloc(NSB * 4);
    int*    sbbase = (int*)   alloc(NSB * 4);
    int*    browb  = (int*)   alloc((size_t)8 * BCAP * 4);
    int*    bcolb  = (int*)   alloc((size_t)8 * BCAP * 4);
    int*    sbrow  = (int*)   alloc((size_t)NSB * SBCAP * 4);
    int*    sbcol  = (int*)   alloc((size_t)NSB * SBCAP * 4);
    int*    ghist  = (int*)   alloc((size_t)NSB * SBROWS * 4);
    int*    ccol   = (int*)   alloc((size_t)CCAP * 4);
    unsigned short* w1f = (unsigned short*)alloc(2048 * 8 * 2);
    unsigned short* w2f = (unsigned short*)alloc(1536 * 8 * 2);
    uint4* ha   = (uint4*)alloc((size_t)(n + 1) * NF * 2);   // bf16 g ping (+zero row)
    uint4* hbuf = (uint4*)alloc((size_t)(n + 1) * NF * 2);   // bf16 g pong (+zero row)
    float* y    = (float*)alloc((size_t)n * NF * 4);         // f32 accumulator

    hipMemsetAsync(bcnt, 0, 8 * 4, stream);
    hipMemsetAsync(sbcnt, 0, NSB * 4, stream);

    const int* rows = ei;
    const int* cols = ei + E;

    k_bin   <<<(E + BINB - 1) / BINB, 256, 0, stream>>>(rows, cols, bcnt, browb, bcolb, E);
    k_bin98 <<<640, 256, 0, stream>>>(browb, bcolb, bcnt, sbcnt, sbrow, sbcol);
    k_hist  <<<NSB, 256, 0, stream>>>(sbrow, sbcnt, ghist, sbtot);
    k_scansb<<<1, 1024, 0, stream>>>(sbtot, sbbase, rp, n);
    k_csr   <<<NSB, 256, 0, stream>>>(sbrow, sbcol, sbcnt, ghist, sbbase, rp, drd, ccol, n);
    k_pack  <<<14, 256, 0, stream>>>(W1, W2, w1f, w2f);

    int nchunk = n * 8;
    k_init<<<(nchunk + 8 + 255) / 256, 256, 0, stream>>>((const float4*)x, (float4*)y,
                                                         ha, hbuf, drd, nchunk);

    uint4* cur = ha;
    uint4* nxt = hbuf;
    int spmm_blocks = (n + 15) / 16;   // 4 rows/wave, 4 waves/block
    for (int it = 0; it < ORDER_C; ++it) {
        bool acc = (it & 1) != 0;
        bool wg  = (it != ORDER_C - 1);
        if (acc && wg)
            k_spmm<true, true><<<spmm_blocks, 256, 0, stream>>>((const uint2*)cur, (uint2*)nxt,
                                                                (float4*)y, rp, ccol, drd, n);
        else if (acc)
            k_spmm<true, false><<<spmm_blocks, 256, 0, stream>>>((const uint2*)cur, (uint2*)nxt,
                                                                 (float4*)y, rp, ccol, drd, n);
        else
            k_spmm<false, true><<<spmm_blocks, 256, 0, stream>>>((const uint2*)cur, (uint2*)nxt,
                                                                 (float4*)y, rp, ccol, drd, n);
        uint4* tswap = cur; cur = nxt; nxt = tswap;
    }

    k_mlp<<<(n + 63) / 64, 256, 0, stream>>>((const float4*)y, (const short8*)w1f,
                                             (const short8*)w2f, b1, b2, out, n);
}